// Round 1
// baseline (817.334 us; speedup 1.0000x reference)
//
#include <hip/hip_runtime.h>
#include <cstdint>

typedef _Float16 f16x2 __attribute__((ext_vector_type(2)));

// Clamp-free fast activations: gate pre-activations here are |x| <~ 15.
__device__ __forceinline__ float fsig(float x) {
  return __fdividef(1.f, 1.f + __expf(-x));
}
__device__ __forceinline__ float ftanh_(float x) {
  return fmaf(2.f, fsig(x + x), -1.f);
}
__device__ __forceinline__ int packf16(float a, float b) {
  f16x2 p; p.x = (_Float16)a; p.y = (_Float16)b;
  return __builtin_bit_cast(int, p);
}
__device__ __forceinline__ float dot2(int w, int h, float acc) {
  return __builtin_amdgcn_fdot2(__builtin_bit_cast(f16x2, w),
                                __builtin_bit_cast(f16x2, h), acc, false);
}
// Quad-lane permute via DPP: VALU-latency (~4 cyc) vs ds_swizzle's LDS
// latency (~100+ cyc). q = t&3 lanes ARE the DPP quads.
template <int CTRL>
__device__ __forceinline__ float qp(float v) {
  return __int_as_float(__builtin_amdgcn_update_dpp(
      0, __float_as_int(v), CTRL, 0xF, 0xF, true));
}
#define QP_X1 0xB1  // quad_perm [1,0,3,2]  (lane ^ 1)
#define QP_X2 0x4E  // quad_perm [2,3,0,1]  (lane ^ 2)

// ---------------------------------------------------------------------------
// Layer 1: R10..R13 structure, ONE change — x row loaded as float4 chunks
// (4 dwordx4/thread, chunk+1 prefetch) instead of 16 per-step scalar loads
// at 64-B lane stride. At 2 waves/SIMD the old per-step loads were
// latency-exposed; now in-loop global traffic is prefetched a full 4-step
// chunk ahead. Inner 4 steps unrolled so the xs[] index is static (no
// scratch).
// ---------------------------------------------------------------------------
__global__ __launch_bounds__(256, 2) void lstm1_kernel(
    const float* __restrict__ x, const float* __restrict__ Wih,
    const float* __restrict__ Whh, const float* __restrict__ bih,
    const float* __restrict__ bhh, int4* __restrict__ h1out) {
  const int n = blockIdx.x * 256 + threadIdx.x;  // chain id = b*S + s

  int whh2[128];
#pragma unroll
  for (int r = 0; r < 32; ++r) {
#pragma unroll
    for (int j = 0; j < 4; ++j) {
      float2 v = ((const float2*)(Whh + r * 8))[j];
      whh2[r * 4 + j] = packf16(v.x, v.y);
    }
  }
  int wxb[32];
#pragma unroll
  for (int r = 0; r < 32; ++r) wxb[r] = packf16(Wih[r], bih[r] + bhh[r]);

#pragma unroll
  for (int i = 0; i < 128; i += 8)
    asm volatile("" : "+v"(whh2[i]), "+v"(whh2[i + 1]), "+v"(whh2[i + 2]),
                      "+v"(whh2[i + 3]), "+v"(whh2[i + 4]), "+v"(whh2[i + 5]),
                      "+v"(whh2[i + 6]), "+v"(whh2[i + 7]));
#pragma unroll
  for (int i = 0; i < 32; i += 8)
    asm volatile("" : "+v"(wxb[i]), "+v"(wxb[i + 1]), "+v"(wxb[i + 2]),
                      "+v"(wxb[i + 3]), "+v"(wxb[i + 4]), "+v"(wxb[i + 5]),
                      "+v"(wxb[i + 6]), "+v"(wxb[i + 7]));

  const float4* __restrict__ xp4 = (const float4*)(x + (size_t)n * 16);
  float c[8];
  int h2[4];
#pragma unroll
  for (int k = 0; k < 8; ++k) c[k] = 0.f;
#pragma unroll
  for (int j = 0; j < 4; ++j) h2[j] = 0;

  float4 xcur = xp4[0];
#pragma unroll 1
  for (int tt = 0; tt < 4; ++tt) {
    float4 xnxt = xp4[(tt + 1) & 3];  // prefetch next chunk (wraps: harmless)
    float xs[4] = {xcur.x, xcur.y, xcur.z, xcur.w};
#pragma unroll
    for (int u = 0; u < 4; ++u) {
      const int xt1 = packf16(xs[u], 1.f);
      float hn[8];
#pragma unroll
      for (int k = 0; k < 8; ++k) {
        float acc[4];
#pragma unroll
        for (int gi = 0; gi < 4; ++gi) {
          const int r = gi * 8 + k;
          float a = dot2(wxb[r], xt1, 0.f);
          a = dot2(whh2[r * 4 + 0], h2[0], a);
          a = dot2(whh2[r * 4 + 1], h2[1], a);
          a = dot2(whh2[r * 4 + 2], h2[2], a);
          a = dot2(whh2[r * 4 + 3], h2[3], a);
          acc[gi] = a;
        }
        float iv = fsig(acc[0]), fv = fsig(acc[1]);
        float gv = ftanh_(acc[2]), ov = fsig(acc[3]);
        c[k] = fmaf(fv, c[k], iv * gv);
        hn[k] = ov * ftanh_(c[k]);
      }
#pragma unroll
      for (int j = 0; j < 4; ++j) h2[j] = packf16(hn[2 * j], hn[2 * j + 1]);
    }
    xcur = xnxt;
  }
  int4 o;
  o.x = h2[0]; o.y = h2[1]; o.z = h2[2]; o.w = h2[3];
  h1out[n] = o;
}

// ---------------------------------------------------------------------------
// Layer 2: R14 structure with TWO changes:
//  (1) AGPR un-parking. VGPR_Count=60 showed the 68 packed-weight regs
//      (w[64]+wig[4]) were parked in AGPRs -> ~68 v_accvgpr_read/step
//      (~270 cyc/step of VALU tax at 2 waves/SIMD). launch_bounds(512,1)
//      (grid is 1 block/CU = 8 waves/CU anyway) + in-loop "+v" pins force
//      true VGPR residency (~130 regs needed, budget is 256).
//  (2) x path: sX LDS staging dropped; x_t is a block-uniform 16-B load
//      from global (scalar-cache path), prefetched TWO steps deep. The old
//      xc ds_read was issued at loop bottom and consumed at loop top, so it
//      serialized into the loop-top lgkm drain with the hq reads; now bx
//      issues inside the hq ds_read shadow.
// Everything else (quad K-split, DPP reduce/gather, one barrier/step) is
// byte-identical to R14.
// ---------------------------------------------------------------------------
__global__ __launch_bounds__(512, 1) void lstm2_kernel(
    const int4* __restrict__ h1, const float* __restrict__ Wih,
    const float* __restrict__ Whh, const float* __restrict__ bih,
    const float* __restrict__ bhh, const float* __restrict__ Wd1,
    const float* __restrict__ bd1, const float* __restrict__ Wd2,
    const float* __restrict__ bd2, float* __restrict__ out) {
  __shared__ __align__(16) _Float16 sH[2][128];  // 512 B double-buffered h
  const int b = blockIdx.x;
  const int t = threadIdx.x;
  const int m = t >> 2;  // hidden index
  const int q = t & 3;   // K-quarter and result slot (= DPP quad lane)
  const int G = ((q & 1) << 1) | (q >> 1);  // gate this thread finalizes
  const bool sel0 = (q & 1) != 0;
  const bool sel1 = (q & 2) != 0;
  const bool isq0 = (q == 0);
  const bool isq1 = (q == 1);  // G==2 (tanh gate)

  // K-quarter q of all four gate rows of index m: w[g*16+j]
  int w[64];
#pragma unroll
  for (int g = 0; g < 4; ++g) {
    const float2* p = (const float2*)(Whh + (size_t)(g * 128 + m) * 128 + q * 32);
#pragma unroll
    for (int j = 0; j < 16; ++j) {
      float2 v = p[j];
      w[g * 16 + j] = packf16(v.x, v.y);
    }
  }

  // x-row + bias for the gate this thread finalizes (row G*128+m)
  int wig[4];
  {
    const float2* pi = (const float2*)(Wih + (size_t)(G * 128 + m) * 8);
#pragma unroll
    for (int j = 0; j < 4; ++j) {
      float2 v = pi[j];
      wig[j] = packf16(v.x, v.y);
    }
  }
  const float bias = bih[G * 128 + m] + bhh[G * 128 + m];

  int hq[16];  // this thread's h-quarter (32 f16)
#pragma unroll
  for (int i = 0; i < 16; ++i) hq[i] = 0;
  float c = 0.f;  // cell state for index m (replicated across the quad)

  // x stream: block-uniform, recurrence-independent -> 2-step-deep prefetch
  const int4* __restrict__ xg = h1 + (size_t)b * 1024;
  int4 xc = xg[0];
  int4 xn = xg[1];

#pragma unroll 1
  for (int ts = 0; ts < 1024; ++ts) {
    // Keep the weights VGPR-resident every iteration (defeat AGPR parking).
#pragma unroll
    for (int i = 0; i < 64; i += 8)
      asm volatile("" : "+v"(w[i]), "+v"(w[i + 1]), "+v"(w[i + 2]),
                        "+v"(w[i + 3]), "+v"(w[i + 4]), "+v"(w[i + 5]),
                        "+v"(w[i + 6]), "+v"(w[i + 7]));
    asm volatile("" : "+v"(wig[0]), "+v"(wig[1]), "+v"(wig[2]), "+v"(wig[3]));

    // x-part + bias for this thread's final gate (independent of hq reads)
    float bx = bias;
    bx = dot2(wig[0], xc.x, bx);
    bx = dot2(wig[1], xc.y, bx);
    bx = dot2(wig[2], xc.z, bx);
    bx = dot2(wig[3], xc.w, bx);

    // quarter-dots of all 4 gate rows (64 dot2, 4 independent chains)
    float R0 = 0.f, R1 = 0.f, R2 = 0.f, R3 = 0.f;
#pragma unroll
    for (int j = 0; j < 16; ++j) {
      R0 = dot2(w[j], hq[j], R0);
      R1 = dot2(w[16 + j], hq[j], R1);
      R2 = dot2(w[32 + j], hq[j], R2);
      R3 = dot2(w[48 + j], hq[j], R3);
    }
    // transpose-reduce across the quad (DPP): thread q ends with gate G's sum
    float s0 = sel0 ? R0 : R2, s1 = sel0 ? R1 : R3;   // send
    float k0 = sel0 ? R2 : R0, k1 = sel0 ? R3 : R1;   // keep
    float S0 = k0 + qp<QP_X1>(s0);
    float S1 = k1 + qp<QP_X1>(s1);
    float s2 = sel1 ? S0 : S1;
    float k2 = sel1 ? S1 : S0;
    float S = k2 + qp<QP_X2>(s2) + bx;

    // activation: gate G (tanh iff q==1) via 2*sig(2x)-1
    float u = isq1 ? (S + S) : S;
    float sg = fsig(u);
    float act = isq1 ? fmaf(2.f, sg, -1.f) : sg;

    // gather all 4 activated gates into every quad lane (DPP)
    float v0 = act;
    float v1 = qp<QP_X1>(v0);
    float v2 = qp<QP_X2>(v0);
    float v3 = qp<QP_X2>(v1);
    float p01 = sel0 ? v1 : v0, p23 = sel0 ? v3 : v2;
    float q01 = sel0 ? v0 : v1, q23 = sel0 ? v2 : v3;
    float iv = sel1 ? p23 : p01;
    float fv = sel1 ? p01 : p23;
    float gv = sel1 ? q23 : q01;
    float ov = sel1 ? q01 : q23;

    c = fmaf(fv, c, iv * gv);
    float hx = ov * ftanh_(c);
    if (isq0) sH[ts & 1][m] = (_Float16)hx;  // one writer per index
    __syncthreads();                         // the only barrier per step

    {  // refresh this thread's h-quarter (4 x ds_read_b128); rotate x regs
      const int4* src = (const int4*)(&sH[ts & 1][q * 32]);
      int4 A = src[0], B = src[1], C = src[2], D = src[3];
      hq[0] = A.x;  hq[1] = A.y;  hq[2] = A.z;  hq[3] = A.w;
      hq[4] = B.x;  hq[5] = B.y;  hq[6] = B.z;  hq[7] = B.w;
      hq[8] = C.x;  hq[9] = C.y;  hq[10] = C.z; hq[11] = C.w;
      hq[12] = D.x; hq[13] = D.y; hq[14] = D.z; hq[15] = D.w;
      xc = xn;
      xn = xg[ts < 1022 ? ts + 2 : 1023];
    }
  }

  // Epilogue: out[b] = (h @ Wd1.T + bd1) @ Wd2.T + bd2; h_T is in sH[1].
  if (t < 64) {
    float a = bd1[t];
#pragma unroll
    for (int k = 0; k < 128; ++k)
      a = fmaf(Wd1[t * 128 + k], (float)sH[1][k], a);
    float v = a * Wd2[t];
#pragma unroll
    for (int off = 32; off > 0; off >>= 1) v += __shfl_down(v, off);
    if (t == 0) out[b] = v + bd2[0];
  }
}

extern "C" void kernel_launch(void* const* d_in, const int* in_sizes, int n_in,
                              void* d_out, int out_size, void* d_ws, size_t ws_size,
                              hipStream_t stream) {
  const float* x    = (const float*)d_in[0];
  // d_in[1] is the unused python scalar `data`
  const float* Wih1 = (const float*)d_in[2];
  const float* Whh1 = (const float*)d_in[3];
  const float* bih1 = (const float*)d_in[4];
  const float* bhh1 = (const float*)d_in[5];
  const float* Wih2 = (const float*)d_in[6];
  const float* Whh2 = (const float*)d_in[7];
  const float* bih2 = (const float*)d_in[8];
  const float* bhh2 = (const float*)d_in[9];
  const float* W1   = (const float*)d_in[10];
  const float* b1   = (const float*)d_in[11];
  const float* W2   = (const float*)d_in[12];
  const float* b2   = (const float*)d_in[13];
  float* out = (float*)d_out;

  int4* h1 = (int4*)d_ws;  // 262144 chains x 8 f16 = 4 MB scratch

  lstm1_kernel<<<1024, 256, 0, stream>>>(x, Wih1, Whh1, bih1, bhh1, h1);
  lstm2_kernel<<<256, 512, 0, stream>>>(h1, Wih2, Whh2, bih2, bhh2,
                                        W1, b1, W2, b2, out);
}

// Round 2
// 786.438 us; speedup vs baseline: 1.0393x; 1.0393x over previous
//
#include <hip/hip_runtime.h>
#include <cstdint>

typedef _Float16 f16x2 __attribute__((ext_vector_type(2)));

// Clamp-free fast activations: gate pre-activations here are |x| <~ 15.
__device__ __forceinline__ float fsig(float x) {
  return __fdividef(1.f, 1.f + __expf(-x));
}
__device__ __forceinline__ float ftanh_(float x) {
  return fmaf(2.f, fsig(x + x), -1.f);
}
__device__ __forceinline__ int packf16(float a, float b) {
  f16x2 p; p.x = (_Float16)a; p.y = (_Float16)b;
  return __builtin_bit_cast(int, p);
}
__device__ __forceinline__ float dot2(int w, int h, float acc) {
  return __builtin_amdgcn_fdot2(__builtin_bit_cast(f16x2, w),
                                __builtin_bit_cast(f16x2, h), acc, false);
}
// Pair-lane permute via DPP quad_perm [1,0,3,2] (lane ^ 1): ~4 cyc VALU.
template <int CTRL>
__device__ __forceinline__ float qp(float v) {
  return __int_as_float(__builtin_amdgcn_update_dpp(
      0, __float_as_int(v), CTRL, 0xF, 0xF, true));
}
#define QP_X1 0xB1  // quad_perm [1,0,3,2]  (lane ^ 1)

// ---------------------------------------------------------------------------
// Layer 1: original R0 session version (measured ~109 us); R1's float4
// restructure regressed ~10 us -> reverted.
// ---------------------------------------------------------------------------
__global__ __launch_bounds__(256, 2) void lstm1_kernel(
    const float* __restrict__ x, const float* __restrict__ Wih,
    const float* __restrict__ Whh, const float* __restrict__ bih,
    const float* __restrict__ bhh, int4* __restrict__ h1out) {
  const int n = blockIdx.x * 256 + threadIdx.x;  // chain id = b*S + s

  int whh2[128];
#pragma unroll
  for (int r = 0; r < 32; ++r) {
#pragma unroll
    for (int j = 0; j < 4; ++j) {
      float2 v = ((const float2*)(Whh + r * 8))[j];
      whh2[r * 4 + j] = packf16(v.x, v.y);
    }
  }
  int wxb[32];
#pragma unroll
  for (int r = 0; r < 32; ++r) wxb[r] = packf16(Wih[r], bih[r] + bhh[r]);

#pragma unroll
  for (int i = 0; i < 128; i += 8)
    asm volatile("" : "+v"(whh2[i]), "+v"(whh2[i + 1]), "+v"(whh2[i + 2]),
                      "+v"(whh2[i + 3]), "+v"(whh2[i + 4]), "+v"(whh2[i + 5]),
                      "+v"(whh2[i + 6]), "+v"(whh2[i + 7]));
#pragma unroll
  for (int i = 0; i < 32; i += 8)
    asm volatile("" : "+v"(wxb[i]), "+v"(wxb[i + 1]), "+v"(wxb[i + 2]),
                      "+v"(wxb[i + 3]), "+v"(wxb[i + 4]), "+v"(wxb[i + 5]),
                      "+v"(wxb[i + 6]), "+v"(wxb[i + 7]));

  const float* __restrict__ xp = x + (size_t)n * 16;
  float c[8];
  int h2[4];
#pragma unroll
  for (int k = 0; k < 8; ++k) c[k] = 0.f;
#pragma unroll
  for (int j = 0; j < 4; ++j) h2[j] = 0;

  float xv = xp[0];
#pragma unroll 1
  for (int t = 0; t < 16; ++t) {
    float xn = xp[(t + 1) & 15];
    const int xt1 = packf16(xv, 1.f);
    float hn[8];
#pragma unroll
    for (int k = 0; k < 8; ++k) {
      float acc[4];
#pragma unroll
      for (int gi = 0; gi < 4; ++gi) {
        const int r = gi * 8 + k;
        float a = dot2(wxb[r], xt1, 0.f);
        a = dot2(whh2[r * 4 + 0], h2[0], a);
        a = dot2(whh2[r * 4 + 1], h2[1], a);
        a = dot2(whh2[r * 4 + 2], h2[2], a);
        a = dot2(whh2[r * 4 + 3], h2[3], a);
        acc[gi] = a;
      }
      float iv = fsig(acc[0]), fv = fsig(acc[1]);
      float gv = ftanh_(acc[2]), ov = fsig(acc[3]);
      c[k] = fmaf(fv, c[k], iv * gv);
      hn[k] = ov * ftanh_(c[k]);
    }
#pragma unroll
    for (int j = 0; j < 4; ++j) h2[j] = packf16(hn[2 * j], hn[2 * j + 1]);
    xv = xn;
  }
  int4 o;
  o.x = h2[0]; o.y = h2[1]; o.z = h2[2]; o.w = h2[3];
  h1out[n] = o;
}

// ---------------------------------------------------------------------------
// Layer 2 RESTRUCTURE: 256 threads/block (4 waves, 1 wave/SIMD), K-HALF per
// thread (was 512 threads / K-quarter).
//
// R1 post-mortem: runtime was invariant to +-270 cyc of VALU issue and to
// the x-path latency => NOT issue-bound. The 1632 cyc/step is the per-step
// serial chain (ds_read -> dot chain -> DPP reduce -> sigmoid -> gather ->
// tanh -> ds_write -> barrier) PLUS 8-wave barrier skew where 2 lock-stepped
// waves share each SIMD's issue port. This version:
//   - 4 waves on 4 different SIMDs: barrier-arrival skew from intra-SIMD
//     issue serialization disappears; issue (~460 cyc, doubled per-thread
//     work) stays under the chain, which R1 proved has slack.
//   - pair (lane^1) reduce: 1 DPP hop (was 2) + gather 2 hops (was 3+8 sel).
//   - dot work split into 8 chains of depth 16 (tree) to keep the dep chain
//     no deeper than before.
// ---------------------------------------------------------------------------
__global__ __launch_bounds__(256, 1) void lstm2_kernel(
    const int4* __restrict__ h1, const float* __restrict__ Wih,
    const float* __restrict__ Whh, const float* __restrict__ bih,
    const float* __restrict__ bhh, const float* __restrict__ Wd1,
    const float* __restrict__ bd1, const float* __restrict__ Wd2,
    const float* __restrict__ bd2, float* __restrict__ out) {
  __shared__ __align__(16) _Float16 sH[2][128];  // 512 B double-buffered h
  const int b = blockIdx.x;
  const int t = threadIdx.x;
  const int m = t >> 1;  // hidden index (0..127)
  const int q = t & 1;   // K-half and DPP pair lane
  const bool isq1 = (q == 1);

  // K-half q of all four gate rows of index m: w[g*32+j], j=0..31
  int w[128];
#pragma unroll
  for (int g = 0; g < 4; ++g) {
    const float2* p = (const float2*)(Whh + (size_t)(g * 128 + m) * 128 + q * 64);
#pragma unroll
    for (int j = 0; j < 32; ++j) {
      float2 v = p[j];
      w[g * 32 + j] = packf16(v.x, v.y);
    }
  }
  // Force materialization here (defeat in-loop rematerialization).
#pragma unroll
  for (int i = 0; i < 128; i += 8)
    asm volatile("" : "+v"(w[i]), "+v"(w[i + 1]), "+v"(w[i + 2]),
                      "+v"(w[i + 3]), "+v"(w[i + 4]), "+v"(w[i + 5]),
                      "+v"(w[i + 6]), "+v"(w[i + 7]));

  // x rows + biases for the two gates this thread finalizes:
  // gate A = 2q (i or g), gate B = 2q+1 (f or o).
  int wigA[4], wigB[4];
  float biasA, biasB;
  {
    const int rowA = (2 * q) * 128 + m;
    const int rowB = (2 * q + 1) * 128 + m;
    const float2* pa = (const float2*)(Wih + (size_t)rowA * 8);
    const float2* pb = (const float2*)(Wih + (size_t)rowB * 8);
#pragma unroll
    for (int j = 0; j < 4; ++j) {
      float2 va = pa[j], vb = pb[j];
      wigA[j] = packf16(va.x, va.y);
      wigB[j] = packf16(vb.x, vb.y);
    }
    biasA = bih[rowA] + bhh[rowA];
    biasB = bih[rowB] + bhh[rowB];
  }

  int hq[32];  // this thread's h-half (64 f16)
#pragma unroll
  for (int i = 0; i < 32; ++i) hq[i] = 0;
  float c = 0.f;  // cell state for index m (replicated across the pair)

  // x stream: block-uniform, recurrence-independent -> 2-step-deep prefetch
  const int4* __restrict__ xg = h1 + (size_t)b * 1024;
  int4 xc = xg[0];
  int4 xn = xg[1];

#pragma unroll 1
  for (int ts = 0; ts < 1024; ++ts) {
    // x-part + bias for this thread's two final gates (off the h chain)
    float bxA = biasA, bxB = biasB;
    bxA = dot2(wigA[0], xc.x, bxA);
    bxA = dot2(wigA[1], xc.y, bxA);
    bxA = dot2(wigA[2], xc.z, bxA);
    bxA = dot2(wigA[3], xc.w, bxA);
    bxB = dot2(wigB[0], xc.x, bxB);
    bxB = dot2(wigB[1], xc.y, bxB);
    bxB = dot2(wigB[2], xc.z, bxB);
    bxB = dot2(wigB[3], xc.w, bxB);

    // half-dots of all 4 gate rows: 128 dot2 in 8 chains of depth 16
    float R0a = 0.f, R1a = 0.f, R2a = 0.f, R3a = 0.f;
    float R0b = 0.f, R1b = 0.f, R2b = 0.f, R3b = 0.f;
#pragma unroll
    for (int j = 0; j < 16; ++j) {
      R0a = dot2(w[j], hq[j], R0a);
      R1a = dot2(w[32 + j], hq[j], R1a);
      R2a = dot2(w[64 + j], hq[j], R2a);
      R3a = dot2(w[96 + j], hq[j], R3a);
    }
#pragma unroll
    for (int j = 16; j < 32; ++j) {
      R0b = dot2(w[j], hq[j], R0b);
      R1b = dot2(w[32 + j], hq[j], R1b);
      R2b = dot2(w[64 + j], hq[j], R2b);
      R3b = dot2(w[96 + j], hq[j], R3b);
    }
    float R0 = R0a + R0b, R1 = R1a + R1b;
    float R2 = R2a + R2b, R3 = R3a + R3b;

    // pair reduce (1 DPP hop each): lane0 ends with gates 0,1; lane1 with 2,3
    float vA = isq1 ? R0 : R2;              // send partner what it finalizes
    float Sa = (isq1 ? R2 : R0) + qp<QP_X1>(vA) + bxA;
    float vB = isq1 ? R1 : R3;
    float Sb = (isq1 ? R3 : R1) + qp<QP_X1>(vB) + bxB;

    // activations: lane0: iv=sig(Sa), fv=sig(Sb); lane1: gv=tanh(Sa), ov=sig(Sb)
    float ua = isq1 ? (Sa + Sa) : Sa;
    float sga = fsig(ua);
    float actA = isq1 ? fmaf(2.f, sga, -1.f) : sga;
    float actB = fsig(Sb);

    // gather the partner's two activated gates (2 DPP hops)
    float ga = qp<QP_X1>(actA);
    float gb = qp<QP_X1>(actB);
    float iv = isq1 ? ga : actA;
    float gv = isq1 ? actA : ga;
    float fv = isq1 ? gb : actB;
    float ov = isq1 ? actB : gb;

    c = fmaf(fv, c, iv * gv);
    float hx = ov * ftanh_(c);
    if (!isq1) sH[ts & 1][m] = (_Float16)hx;  // one writer per index
    __syncthreads();                          // the only barrier per step

    {  // refresh this thread's h-half (8 x ds_read_b128); rotate x regs
      const int4* src = (const int4*)(&sH[ts & 1][q * 64]);
      int4 A = src[0], B = src[1], C = src[2], D = src[3];
      int4 E = src[4], F = src[5], G2 = src[6], H = src[7];
      hq[0] = A.x;   hq[1] = A.y;   hq[2] = A.z;   hq[3] = A.w;
      hq[4] = B.x;   hq[5] = B.y;   hq[6] = B.z;   hq[7] = B.w;
      hq[8] = C.x;   hq[9] = C.y;   hq[10] = C.z;  hq[11] = C.w;
      hq[12] = D.x;  hq[13] = D.y;  hq[14] = D.z;  hq[15] = D.w;
      hq[16] = E.x;  hq[17] = E.y;  hq[18] = E.z;  hq[19] = E.w;
      hq[20] = F.x;  hq[21] = F.y;  hq[22] = F.z;  hq[23] = F.w;
      hq[24] = G2.x; hq[25] = G2.y; hq[26] = G2.z; hq[27] = G2.w;
      hq[28] = H.x;  hq[29] = H.y;  hq[30] = H.z;  hq[31] = H.w;
      xc = xn;
      xn = xg[ts < 1022 ? ts + 2 : 1023];
    }
  }

  // Epilogue: out[b] = (h @ Wd1.T + bd1) @ Wd2.T + bd2; h_T is in sH[1].
  if (t < 64) {
    float a = bd1[t];
#pragma unroll
    for (int k = 0; k < 128; ++k)
      a = fmaf(Wd1[t * 128 + k], (float)sH[1][k], a);
    float v = a * Wd2[t];
#pragma unroll
    for (int off = 32; off > 0; off >>= 1) v += __shfl_down(v, off);
    if (t == 0) out[b] = v + bd2[0];
  }
}

extern "C" void kernel_launch(void* const* d_in, const int* in_sizes, int n_in,
                              void* d_out, int out_size, void* d_ws, size_t ws_size,
                              hipStream_t stream) {
  const float* x    = (const float*)d_in[0];
  // d_in[1] is the unused python scalar `data`
  const float* Wih1 = (const float*)d_in[2];
  const float* Whh1 = (const float*)d_in[3];
  const float* bih1 = (const float*)d_in[4];
  const float* bhh1 = (const float*)d_in[5];
  const float* Wih2 = (const float*)d_in[6];
  const float* Whh2 = (const float*)d_in[7];
  const float* bih2 = (const float*)d_in[8];
  const float* bhh2 = (const float*)d_in[9];
  const float* W1   = (const float*)d_in[10];
  const float* b1   = (const float*)d_in[11];
  const float* W2   = (const float*)d_in[12];
  const float* b2   = (const float*)d_in[13];
  float* out = (float*)d_out;

  int4* h1 = (int4*)d_ws;  // 262144 chains x 8 f16 = 4 MB scratch

  lstm1_kernel<<<1024, 256, 0, stream>>>(x, Wih1, Whh1, bih1, bhh1, h1);
  lstm2_kernel<<<256, 256, 0, stream>>>(h1, Wih2, Whh2, bih2, bhh2,
                                        W1, b1, W2, b2, out);
}

// Round 4
// 659.263 us; speedup vs baseline: 1.2398x; 1.1929x over previous
//
#include <hip/hip_runtime.h>
#include <cstdint>

typedef _Float16 f16x2 __attribute__((ext_vector_type(2)));

#define L2E 1.44269504f

// Activations with log2(e) pre-folded into weights/biases:
// sig2(y) = 1/(1+2^-y)  (y = x*log2e already)
__device__ __forceinline__ float sig2(float y) {
  return __builtin_amdgcn_rcpf(1.f + exp2f(-y));
}
// tanh for runtime (unscaled) cell state c
__device__ __forceinline__ float tanhc(float c) {
  return fmaf(2.f, __builtin_amdgcn_rcpf(1.f + exp2f(c * (-2.f * L2E))), -1.f);
}
__device__ __forceinline__ int packf16(float a, float b) {
  f16x2 p; p.x = (_Float16)a; p.y = (_Float16)b;
  return __builtin_bit_cast(int, p);
}
__device__ __forceinline__ float dot2(int w, int h, float acc) {
  return __builtin_amdgcn_fdot2(__builtin_bit_cast(f16x2, w),
                                __builtin_bit_cast(f16x2, h), acc, false);
}
// Pair-lane permute via DPP quad_perm (lane ^ 1): ~4 cyc VALU.
template <int CTRL>
__device__ __forceinline__ float qp(float v) {
  return __int_as_float(__builtin_amdgcn_update_dpp(
      0, __float_as_int(v), CTRL, 0xF, 0xF, true));
}
#define QP_X1 0xB1  // quad_perm [1,0,3,2]  (lane ^ 1)

// ---------------------------------------------------------------------------
// FUSED kernel (resubmit of R3 — container-side infra failure, no kernel
// evidence against it): phase 1 = lstm1 for this block's 1024 chains (4 per
// thread, 16 steps each, issue-bound ~20 us, x footprint 16 KB/CU ->
// L1-resident), writing h1 directly into sX LDS. Phase 2 = the R2 lstm2
// loop with: 2-step unroll (static sH[0]/sH[1] addresses), no clamp
// cndmask on the x prefetch, log2e/x2 folded into f16 weights+biases so
// sigmoid = exp2+add+rcp (shorter serial chain), rcpf not fdividef.
// Eliminates: the 110-125 us lstm1 dispatch (L1-thrashed at 8 waves/CU),
// the inter-kernel launch gap, and the 4 MB h1 HBM round-trip.
// ---------------------------------------------------------------------------
__global__ __launch_bounds__(256, 1) void fused_kernel(
    const float* __restrict__ x, const float* __restrict__ Wih1,
    const float* __restrict__ Whh1, const float* __restrict__ bih1,
    const float* __restrict__ bhh1, const float* __restrict__ Wih2,
    const float* __restrict__ Whh2, const float* __restrict__ bih2,
    const float* __restrict__ bhh2, const float* __restrict__ Wd1,
    const float* __restrict__ bd1, const float* __restrict__ Wd2,
    const float* __restrict__ bd2, float* __restrict__ out) {
  __shared__ __align__(16) int4 sX[1026];        // h1 sequence (16 KB) + pad
  __shared__ __align__(16) _Float16 sH[2][128];  // double-buffered h

  const int b = blockIdx.x;
  const int t = threadIdx.x;

  // ======================== Phase 1: lstm1 ========================
  {
    // Block-uniform weights, log2e-folded (gate order i,f,g,o; g rows x2).
    int whh2[128];
#pragma unroll
    for (int r = 0; r < 32; ++r) {
      const float s = (r >> 3) == 2 ? 2.f * L2E : L2E;
#pragma unroll
      for (int j = 0; j < 4; ++j) {
        float2 v = ((const float2*)(Whh1 + r * 8))[j];
        whh2[r * 4 + j] = packf16(v.x * s, v.y * s);
      }
    }
    int wxb[32];
#pragma unroll
    for (int r = 0; r < 32; ++r) {
      const float s = (r >> 3) == 2 ? 2.f * L2E : L2E;
      wxb[r] = packf16(Wih1[r] * s, (bih1[r] + bhh1[r]) * s);
    }
#pragma unroll
    for (int i = 0; i < 128; i += 8)
      asm volatile("" : "+v"(whh2[i]), "+v"(whh2[i + 1]), "+v"(whh2[i + 2]),
                        "+v"(whh2[i + 3]), "+v"(whh2[i + 4]), "+v"(whh2[i + 5]),
                        "+v"(whh2[i + 6]), "+v"(whh2[i + 7]));

#pragma unroll 1
    for (int ch = 0; ch < 4; ++ch) {
      const int c = ch * 256 + t;  // chain index within this batch row
      const float* __restrict__ xp = x + ((size_t)b * 1024 + c) * 16;
      float cc[8];
      int h2[4];
#pragma unroll
      for (int k = 0; k < 8; ++k) cc[k] = 0.f;
#pragma unroll
      for (int j = 0; j < 4; ++j) h2[j] = 0;

      float xv = xp[0];
#pragma unroll 1
      for (int u = 0; u < 16; ++u) {
        float xnl = xp[(u + 1) & 15];  // 1-ahead prefetch (same line, L1 hit)
        const int xt1 = packf16(xv, 1.f);
        float hn[8];
#pragma unroll
        for (int k = 0; k < 8; ++k) {
          float acc[4];
#pragma unroll
          for (int gi = 0; gi < 4; ++gi) {
            const int r = gi * 8 + k;
            float a = dot2(wxb[r], xt1, 0.f);
            a = dot2(whh2[r * 4 + 0], h2[0], a);
            a = dot2(whh2[r * 4 + 1], h2[1], a);
            a = dot2(whh2[r * 4 + 2], h2[2], a);
            a = dot2(whh2[r * 4 + 3], h2[3], a);
            acc[gi] = a;
          }
          float iv = sig2(acc[0]), fv = sig2(acc[1]);
          float gv = fmaf(2.f, sig2(acc[2]), -1.f), ov = sig2(acc[3]);
          cc[k] = fmaf(fv, cc[k], iv * gv);
          hn[k] = ov * tanhc(cc[k]);
        }
#pragma unroll
        for (int j = 0; j < 4; ++j) h2[j] = packf16(hn[2 * j], hn[2 * j + 1]);
        xv = xnl;
      }
      int4 o;
      o.x = h2[0]; o.y = h2[1]; o.z = h2[2]; o.w = h2[3];
      sX[c] = o;  // coalesced ds_write_b128, lanes contiguous
    }
  }

  // ======================== Phase 2: lstm2 ========================
  const int m = t >> 1;  // hidden index (0..127)
  const int q = t & 1;   // K-half and DPP pair lane
  const bool isq1 = (q == 1);

  // K-half q of all four gate rows of index m, log2e-folded per gate.
  int w[128];
#pragma unroll
  for (int g = 0; g < 4; ++g) {
    const float s = (g == 2) ? 2.f * L2E : L2E;
    const float2* p = (const float2*)(Whh2 + (size_t)(g * 128 + m) * 128 + q * 64);
#pragma unroll
    for (int j = 0; j < 32; ++j) {
      float2 v = p[j];
      w[g * 32 + j] = packf16(v.x * s, v.y * s);
    }
  }
#pragma unroll
  for (int i = 0; i < 128; i += 8)
    asm volatile("" : "+v"(w[i]), "+v"(w[i + 1]), "+v"(w[i + 2]),
                      "+v"(w[i + 3]), "+v"(w[i + 4]), "+v"(w[i + 5]),
                      "+v"(w[i + 6]), "+v"(w[i + 7]));

  // x rows + biases for the two gates this thread finalizes:
  // gate A = 2q (i or g), gate B = 2q+1 (f or o).
  int wigA[4], wigB[4];
  float biasA, biasB;
  {
    const int gA = 2 * q, gB = 2 * q + 1;
    const float sa = (gA == 2) ? 2.f * L2E : L2E;
    const float sb = L2E;  // gates 1 and 3 are sigmoids
    const int rowA = gA * 128 + m;
    const int rowB = gB * 128 + m;
    const float2* pa = (const float2*)(Wih2 + (size_t)rowA * 8);
    const float2* pb = (const float2*)(Wih2 + (size_t)rowB * 8);
#pragma unroll
    for (int j = 0; j < 4; ++j) {
      float2 va = pa[j], vb = pb[j];
      wigA[j] = packf16(va.x * sa, va.y * sa);
      wigB[j] = packf16(vb.x * sb, vb.y * sb);
    }
    biasA = (bih2[rowA] + bhh2[rowA]) * sa;
    biasB = (bih2[rowB] + bhh2[rowB]) * sb;
  }

  int hq[32];  // this thread's h-half (64 f16)
#pragma unroll
  for (int i = 0; i < 32; ++i) hq[i] = 0;
  float c = 0.f;

  __syncthreads();   // sX fully written
  int4 xc = sX[0];

#define LSTM2_STEP(BUF, NEXT_IDX)                                          \
  {                                                                        \
    float bxA = biasA, bxB = biasB;                                        \
    bxA = dot2(wigA[0], xc.x, bxA);                                        \
    bxA = dot2(wigA[1], xc.y, bxA);                                        \
    bxA = dot2(wigA[2], xc.z, bxA);                                        \
    bxA = dot2(wigA[3], xc.w, bxA);                                        \
    bxB = dot2(wigB[0], xc.x, bxB);                                        \
    bxB = dot2(wigB[1], xc.y, bxB);                                        \
    bxB = dot2(wigB[2], xc.z, bxB);                                        \
    bxB = dot2(wigB[3], xc.w, bxB);                                        \
    float R0a = 0.f, R1a = 0.f, R2a = 0.f, R3a = 0.f;                      \
    float R0b = 0.f, R1b = 0.f, R2b = 0.f, R3b = 0.f;                      \
    _Pragma("unroll")                                                      \
    for (int j = 0; j < 16; ++j) {                                         \
      R0a = dot2(w[j], hq[j], R0a);                                        \
      R1a = dot2(w[32 + j], hq[j], R1a);                                   \
      R2a = dot2(w[64 + j], hq[j], R2a);                                   \
      R3a = dot2(w[96 + j], hq[j], R3a);                                   \
    }                                                                      \
    _Pragma("unroll")                                                      \
    for (int j = 16; j < 32; ++j) {                                        \
      R0b = dot2(w[j], hq[j], R0b);                                        \
      R1b = dot2(w[32 + j], hq[j], R1b);                                   \
      R2b = dot2(w[64 + j], hq[j], R2b);                                   \
      R3b = dot2(w[96 + j], hq[j], R3b);                                   \
    }                                                                      \
    float R0 = R0a + R0b, R1 = R1a + R1b;                                  \
    float R2 = R2a + R2b, R3 = R3a + R3b;                                  \
    float vA = isq1 ? R0 : R2;                                             \
    float Sa = (isq1 ? R2 : R0) + qp<QP_X1>(vA) + bxA;                     \
    float vB = isq1 ? R1 : R3;                                             \
    float Sb = (isq1 ? R3 : R1) + qp<QP_X1>(vB) + bxB;                     \
    float sga = sig2(Sa);                                                  \
    float actA = isq1 ? fmaf(2.f, sga, -1.f) : sga;                        \
    float actB = sig2(Sb);                                                 \
    float ga = qp<QP_X1>(actA);                                            \
    float gb = qp<QP_X1>(actB);                                            \
    float iv = isq1 ? ga : actA;                                           \
    float gv = isq1 ? actA : ga;                                           \
    float fv = isq1 ? gb : actB;                                           \
    float ov = isq1 ? actB : gb;                                           \
    c = fmaf(fv, c, iv * gv);                                              \
    float hx = ov * tanhc(c);                                              \
    if (!isq1) sH[BUF][m] = (_Float16)hx;                                  \
    __syncthreads();                                                       \
    const int4* src = (const int4*)(&sH[BUF][q * 64]);                     \
    int4 A = src[0], Bv = src[1], C = src[2], D = src[3];                  \
    int4 E = src[4], F = src[5], G2 = src[6], H = src[7];                  \
    hq[0] = A.x;   hq[1] = A.y;   hq[2] = A.z;   hq[3] = A.w;              \
    hq[4] = Bv.x;  hq[5] = Bv.y;  hq[6] = Bv.z;  hq[7] = Bv.w;             \
    hq[8] = C.x;   hq[9] = C.y;   hq[10] = C.z;  hq[11] = C.w;             \
    hq[12] = D.x;  hq[13] = D.y;  hq[14] = D.z;  hq[15] = D.w;             \
    hq[16] = E.x;  hq[17] = E.y;  hq[18] = E.z;  hq[19] = E.w;             \
    hq[20] = F.x;  hq[21] = F.y;  hq[22] = F.z;  hq[23] = F.w;             \
    hq[24] = G2.x; hq[25] = G2.y; hq[26] = G2.z; hq[27] = G2.w;            \
    hq[28] = H.x;  hq[29] = H.y;  hq[30] = H.z;  hq[31] = H.w;             \
    xc = sX[NEXT_IDX];                                                     \
  }

#pragma unroll 1
  for (int ts2 = 0; ts2 < 512; ++ts2) {
    LSTM2_STEP(0, 2 * ts2 + 1)
    LSTM2_STEP(1, 2 * ts2 + 2)
  }
#undef LSTM2_STEP

  // Epilogue: out[b] = (h @ Wd1.T + bd1) @ Wd2.T + bd2; h_T is in sH[1].
  if (t < 64) {
    float a = bd1[t];
#pragma unroll
    for (int k = 0; k < 128; ++k)
      a = fmaf(Wd1[t * 128 + k], (float)sH[1][k], a);
    float v = a * Wd2[t];
#pragma unroll
    for (int off = 32; off > 0; off >>= 1) v += __shfl_down(v, off);
    if (t == 0) out[b] = v + bd2[0];
  }
}

extern "C" void kernel_launch(void* const* d_in, const int* in_sizes, int n_in,
                              void* d_out, int out_size, void* d_ws, size_t ws_size,
                              hipStream_t stream) {
  const float* x    = (const float*)d_in[0];
  // d_in[1] is the unused python scalar `data`
  const float* Wih1 = (const float*)d_in[2];
  const float* Whh1 = (const float*)d_in[3];
  const float* bih1 = (const float*)d_in[4];
  const float* bhh1 = (const float*)d_in[5];
  const float* Wih2 = (const float*)d_in[6];
  const float* Whh2 = (const float*)d_in[7];
  const float* bih2 = (const float*)d_in[8];
  const float* bhh2 = (const float*)d_in[9];
  const float* W1   = (const float*)d_in[10];
  const float* b1   = (const float*)d_in[11];
  const float* W2   = (const float*)d_in[12];
  const float* b2   = (const float*)d_in[13];
  float* out = (float*)d_out;

  fused_kernel<<<256, 256, 0, stream>>>(x, Wih1, Whh1, bih1, bhh1,
                                        Wih2, Whh2, bih2, bhh2,
                                        W1, b1, W2, b2, out);
}